// Round 14
// baseline (2364.342 us; speedup 1.0000x reference)
//
#include <hip/hip_runtime.h>

typedef unsigned short u16;
typedef float f32x4 __attribute__((ext_vector_type(4)));
typedef __bf16 bf16x8 __attribute__((ext_vector_type(8)));
typedef u16 u16x8 __attribute__((ext_vector_type(8)));

#define DEV __device__ __forceinline__

DEV u16 f2bf(float f) {
  unsigned u = __builtin_bit_cast(unsigned, f);
  u += 0x7fffu + ((u >> 16) & 1u);
  return (u16)(u >> 16);
}
DEV float bf2f(u16 b) { return __builtin_bit_cast(float, (unsigned)b << 16); }

DEV float wsum(float v) {
#pragma unroll
  for (int o = 32; o > 0; o >>= 1) v += __shfl_xor(v, o, 64);
  return v;
}
DEV float gmax16(float v) {
#pragma unroll
  for (int o = 8; o > 0; o >>= 1) v = fmaxf(v, __shfl_xor(v, o, 64));
  return v;
}
DEV float gsum16(float v) {
#pragma unroll
  for (int o = 8; o > 0; o >>= 1) v += __shfl_xor(v, o, 64);
  return v;
}

DEV void gld16(const void* g, void* l) {
  __builtin_amdgcn_global_load_lds((const __attribute__((address_space(1))) void*)g,
                                   (__attribute__((address_space(3))) void*)l, 16, 0, 0);
}

template <int N>
DEV void vwait() {
  if constexpr (N == 0) asm volatile("s_waitcnt vmcnt(0)" ::: "memory");
  else if constexpr (N == 2) asm volatile("s_waitcnt vmcnt(2)" ::: "memory");
  else if constexpr (N == 4) asm volatile("s_waitcnt vmcnt(4)" ::: "memory");
  else asm volatile("s_waitcnt vmcnt(6)" ::: "memory");
}

// M-major within N + bijective XCD-chunked swizzle.
DEV void remap_bxy(int& bx, int& by) {
  const int gx = gridDim.x, gy = gridDim.y;
  const int flat = blockIdx.y * gx + blockIdx.x;
  const int nwg = gx * gy;
  const int q = nwg >> 3, r = nwg & 7;
  const int xcd = flat & 7, li = flat >> 3;
  const int wg = (xcd < r ? xcd * (q + 1) : r * (q + 1) + (xcd - r) * q) + li;
  by = wg % gy;  // M tile (inner)
  bx = wg / gy;  // N tile (outer)
}

// ---------------------------------------------------------------------------
// NT GEMM (2-barrier, BK = 64 or 128). W = blocks/CU.
// MODE 0: Cb = bf16(acc (+bias[col]) (+bf16 resid[row][col]))   (bf16 out)
// MODE 1: Cb = bf16(relu(acc + bias[col]))                      (ffn1)
// MODE 2: scatter bf16 q/k -> [B,H,S,DK]; V -> LDS-transposed [B,H,DK,S]
// MODE 3: like MODE 2 but dual-A: cols >= 1024 read A2 (cross-attn merge)
// ---------------------------------------------------------------------------
template <int BM, int BN, int MODE, int W, int BK>
__global__ __launch_bounds__(256, W) void gemm_k(
    const u16* __restrict__ A, const u16* __restrict__ A2,
    const u16* __restrict__ B, int lda, int ldb, int K,
    const float* __restrict__ bias, const u16* __restrict__ residb,
    int ldc, u16* __restrict__ Cb, u16* __restrict__ qp,
    u16* __restrict__ kp, u16* __restrict__ vp, int n_off) {
  constexpr int FM = BM / 32, FN = BN / 32;
  constexpr int CHA = BM / 8, CHT = (BM + BN) / 8;
  constexpr int KCH = BK / 64;
  __shared__ u16 lds[2][(BM + BN) * BK];
  const int lane = threadIdx.x & 63, wid = threadIdx.x >> 6;
  const int wr = wid >> 1, wc = wid & 1;
  int bx, by;
  remap_bxy(bx, by);
  const u16* Abase = A;
  if constexpr (MODE == 3) {
    if (bx * BN >= 1024) Abase = A2;
  }
  const u16* gA = Abase + (long)(by * BM) * lda;
  const u16* gB = B + (long)(bx * BN) * ldb;

  const f32x4 zero4 = {0.f, 0.f, 0.f, 0.f};
  f32x4 acc[FM][FN];
#pragma unroll
  for (int m = 0; m < FM; ++m)
#pragma unroll
    for (int n = 0; n < FN; ++n) acc[m][n] = zero4;

  const int r8 = lane >> 3, sl = lane & 7;

  auto stage = [&](int buf, int kt) {
#pragma unroll
    for (int sub = 0; sub < KCH; ++sub) {
      const int kb = kt * BK + (sub << 6);
      u16* lbase = &lds[buf][sub * (BM + BN) * 64];
#pragma unroll
      for (int c0 = 0; c0 < CHT; c0 += 4) {
        const int c = c0 + wid;
        u16* l = lbase + (c << 9);
        const u16* g;
        if (c < CHA) {
          int r = (c << 3) + r8;
          g = gA + (long)r * lda + kb + ((sl ^ (r & 7)) << 3);
        } else {
          int r = ((c - CHA) << 3) + r8;
          g = gB + (long)r * ldb + kb + ((sl ^ (r & 7)) << 3);
        }
        gld16(g, l);
      }
    }
  };

  const int KT = K / BK;
  stage(0, 0);
  __syncthreads();
  int cur = 0;
  for (int kt = 0; kt < KT; ++kt) {
    if (kt + 1 < KT) stage(cur ^ 1, kt + 1);
#pragma unroll
    for (int q = 0; q < 2 * KCH; ++q) {
      const int kh = q >> 1, kl = q & 1;
      const u16* lA = &lds[cur][kh * (BM + BN) * 64];
      const u16* lB = lA + (BM << 6);
      bf16x8 af[FM], bv[FN];
#pragma unroll
      for (int m = 0; m < FM; ++m) {
        int r = wr * (BM / 2) + m * 16 + (lane & 15);
        int slot = ((kl << 2) | (lane >> 4)) ^ (r & 7);
        af[m] = *(const bf16x8*)(lA + (r << 6) + (slot << 3));
      }
#pragma unroll
      for (int n = 0; n < FN; ++n) {
        int r = wc * (BN / 2) + n * 16 + (lane & 15);
        int slot = ((kl << 2) | (lane >> 4)) ^ (r & 7);
        bv[n] = *(const bf16x8*)(lB + (r << 6) + (slot << 3));
      }
#pragma unroll
      for (int m = 0; m < FM; ++m)
#pragma unroll
        for (int n = 0; n < FN; ++n)
          acc[m][n] = __builtin_amdgcn_mfma_f32_16x16x32_bf16(af[m], bv[n], acc[m][n], 0, 0, 0);
    }
    __syncthreads();
    cur ^= 1;
  }

  const int rb = by * BM + wr * (BM / 2) + ((lane >> 4) << 2);
  const int cb = bx * BN + wc * (BN / 2) + (lane & 15);
  if constexpr (MODE == 2 || MODE == 3) {
    const bool isV = (bx * BN + n_off) >= 2048;
    if (isV) {
      __syncthreads();
      u16* T = (u16*)&lds[0][0];  // [BN][BM+8]
      constexpr int TS = BM + 8;
#pragma unroll
      for (int m = 0; m < FM; ++m)
#pragma unroll
        for (int n = 0; n < FN; ++n) {
          int cl = wc * (BN / 2) + n * 16 + (lane & 15);
#pragma unroll
          for (int j = 0; j < 4; ++j) {
            int rl = wr * (BM / 2) + m * 16 + ((lane >> 4) << 2) + j;
            T[cl * TS + rl] = f2bf(acc[m][n][j]);
          }
        }
      __syncthreads();
      const int vcb = bx * BN + n_off - 2048;
      const int b = (by * BM) >> 9, s0 = (by * BM) & 511;
#pragma unroll
      for (int p = 0; p < BM * BN / 2048; ++p) {
        int idx = p * 2048 + threadIdx.x * 8;
        int dl = idx / BM, slx = idx & (BM - 1);
        u16x8 o;
#pragma unroll
        for (int e = 0; e < 8; ++e) o[e] = T[dl * TS + slx + e];
        int vc = vcb + dl;
        *(u16x8*)(vp + (((long)b * 16 + (vc >> 6)) * 64 + (vc & 63)) * 512 + s0 + slx) = o;
      }
    } else {
#pragma unroll
      for (int m = 0; m < FM; ++m)
#pragma unroll
        for (int n = 0; n < FN; ++n)
#pragma unroll
          for (int j = 0; j < 4; ++j) {
            const int row = rb + m * 16 + j;
            const int np = cb + n * 16 + n_off;
            const int sel = np >> 10, dim = np & 1023;
            long base = (((long)(row >> 9) * 16 + (dim >> 6)) * 512 + (row & 511)) * 64 + (dim & 63);
            u16 val = f2bf(acc[m][n][j]);
            if (sel == 0) qp[base] = val;
            else kp[base] = val;
          }
    }
  } else {
#pragma unroll
    for (int m = 0; m < FM; ++m)
#pragma unroll
      for (int n = 0; n < FN; ++n)
#pragma unroll
        for (int j = 0; j < 4; ++j) {
          const int row = rb + m * 16 + j;
          const int col = cb + n * 16;
          float v = acc[m][n][j];
          if constexpr (MODE == 0) {
            if (bias) v += bias[col];
            if (residb) v += bf2f(residb[(long)row * ldc + col]);
            Cb[(long)row * ldc + col] = f2bf(v);
          } else {
            Cb[(long)row * ldc + col] = f2bf(fmaxf(v + bias[col], 0.f));
          }
        }
  }
}

// ---------------------------------------------------------------------------
// 256x256 8-wave deep-pipelined NT GEMM (vocab projection) — R5 schedule.
// ---------------------------------------------------------------------------
__global__ __launch_bounds__(512, 1) void gemm256_k(
    const u16* __restrict__ A, const u16* __restrict__ B, int lda, int ldb, int K,
    float* __restrict__ Cf, int ldc) {
  __shared__ u16 As[2][256 * 64];
  __shared__ u16 Bs[2][256 * 64];
  const int lane = threadIdx.x & 63, wid = threadIdx.x >> 6;
  const int wr = wid >> 2, wc = wid & 3;  // 2M x 4N waves
  int bx, by;
  remap_bxy(bx, by);
  const u16* gA = A + (long)(by * 256) * lda;
  const u16* gB = B + (long)(bx * 256) * ldb;

  const f32x4 z4 = {0.f, 0.f, 0.f, 0.f};
  f32x4 acc[8][4];
#pragma unroll
  for (int m = 0; m < 8; ++m)
#pragma unroll
    for (int n = 0; n < 4; ++n) acc[m][n] = z4;

  const int ssl = lane & 7;

  auto stageH = [&](int t, int h) {
    const int kb = t << 6;
    const int buf = t & 1;
    const bool isA = (h == 0) || (h == 3);
    u16* ldsb = isA ? &As[buf][0] : &Bs[buf][0];
    const u16* gsrc = isA ? gA : gB;
    const int ld = isA ? lda : ldb;
    const int rbase = (h >= 2) ? 128 : 0;
#pragma unroll
    for (int rr = 0; rr < 2; ++rr) {
      const int r0 = rbase + rr * 64 + (wid << 3);
      const int r = r0 + (lane >> 3);
      gld16(gsrc + (long)r * ld + kb + ((ssl ^ (r & 7)) << 3), ldsb + (r0 << 6));
    }
  };

  const int KT = K >> 6;
  stageH(0, 0);
  stageH(0, 1);
  stageH(0, 2);
  stageH(0, 3);

  for (int t = 0; t < KT; ++t) {
    const int buf = t & 1;
    const bool more = (t + 1 < KT);
    const u16* lA = &As[buf][0];
    const u16* lB = &Bs[buf][0];
    bf16x8 af[4][2], bvl[2][2], bvh[2][2];

    // ---- phase 0: mlo x nlo
    vwait<4>();
    __builtin_amdgcn_s_barrier();
    __builtin_amdgcn_sched_barrier(0);
#pragma unroll
    for (int m = 0; m < 4; ++m)
#pragma unroll
      for (int kk = 0; kk < 2; ++kk) {
        int r = wr * 64 + m * 16 + (lane & 15);
        int sg = ((kk << 2) | (lane >> 4)) ^ (r & 7);
        af[m][kk] = *(const bf16x8*)(lA + (r << 6) + (sg << 3));
      }
#pragma unroll
    for (int n = 0; n < 2; ++n)
#pragma unroll
      for (int kk = 0; kk < 2; ++kk) {
        int c = wc * 32 + n * 16 + (lane & 15);
        int sg = ((kk << 2) | (lane >> 4)) ^ (c & 7);
        bvl[n][kk] = *(const bf16x8*)(lB + (c << 6) + (sg << 3));
      }
    if (more) stageH(t + 1, 0);
    __builtin_amdgcn_s_setprio(1);
#pragma unroll
    for (int kk = 0; kk < 2; ++kk)
#pragma unroll
      for (int m = 0; m < 4; ++m)
#pragma unroll
        for (int n = 0; n < 2; ++n)
          acc[m][n] = __builtin_amdgcn_mfma_f32_16x16x32_bf16(af[m][kk], bvl[n][kk], acc[m][n], 0, 0, 0);
    __builtin_amdgcn_s_setprio(0);

    // ---- phase 1: mlo x nhi
    if (more) vwait<4>();
    else vwait<2>();
    __builtin_amdgcn_s_barrier();
    __builtin_amdgcn_sched_barrier(0);
#pragma unroll
    for (int n = 0; n < 2; ++n)
#pragma unroll
      for (int kk = 0; kk < 2; ++kk) {
        int c = 128 + wc * 32 + n * 16 + (lane & 15);
        int sg = ((kk << 2) | (lane >> 4)) ^ (c & 7);
        bvh[n][kk] = *(const bf16x8*)(lB + (c << 6) + (sg << 3));
      }
    if (more) stageH(t + 1, 1);
    __builtin_amdgcn_s_setprio(1);
#pragma unroll
    for (int kk = 0; kk < 2; ++kk)
#pragma unroll
      for (int m = 0; m < 4; ++m)
#pragma unroll
        for (int n = 0; n < 2; ++n)
          acc[m][2 + n] = __builtin_amdgcn_mfma_f32_16x16x32_bf16(af[m][kk], bvh[n][kk], acc[m][2 + n], 0, 0, 0);
    __builtin_amdgcn_s_setprio(0);

    // ---- phase 2: mhi x nhi
    if (more) vwait<4>();
    else vwait<0>();
    __builtin_amdgcn_s_barrier();
    __builtin_amdgcn_sched_barrier(0);
#pragma unroll
    for (int m = 0; m < 4; ++m)
#pragma unroll
      for (int kk = 0; kk < 2; ++kk) {
        int r = 128 + wr * 64 + m * 16 + (lane & 15);
        int sg = ((kk << 2) | (lane >> 4)) ^ (r & 7);
        af[m][kk] = *(const bf16x8*)(lA + (r << 6) + (sg << 3));
      }
    if (more) stageH(t + 1, 2);
    __builtin_amdgcn_s_setprio(1);
#pragma unroll
    for (int kk = 0; kk < 2; ++kk)
#pragma unroll
      for (int m = 0; m < 4; ++m)
#pragma unroll
        for (int n = 0; n < 2; ++n)
          acc[4 + m][2 + n] = __builtin_amdgcn_mfma_f32_16x16x32_bf16(af[m][kk], bvh[n][kk], acc[4 + m][2 + n], 0, 0, 0);
    __builtin_amdgcn_s_setprio(0);

    // ---- phase 3: mhi x nlo
    __builtin_amdgcn_s_barrier();
    __builtin_amdgcn_sched_barrier(0);
    if (more) stageH(t + 1, 3);
    __builtin_amdgcn_s_setprio(1);
#pragma unroll
    for (int kk = 0; kk < 2; ++kk)
#pragma unroll
      for (int m = 0; m < 4; ++m)
#pragma unroll
        for (int n = 0; n < 2; ++n)
          acc[4 + m][n] = __builtin_amdgcn_mfma_f32_16x16x32_bf16(af[m][kk], bvl[n][kk], acc[4 + m][n], 0, 0, 0);
    __builtin_amdgcn_s_setprio(0);
  }

  const int rb = by * 256 + wr * 64 + ((lane >> 4) << 2);
  const int cb = bx * 256 + wc * 32 + (lane & 15);
#pragma unroll
  for (int mi = 0; mi < 8; ++mi)
#pragma unroll
    for (int ni = 0; ni < 4; ++ni)
#pragma unroll
      for (int j = 0; j < 4; ++j) {
        int row = rb + (mi & 3) * 16 + ((mi >> 2) << 7) + j;
        int col = cb + (ni & 1) * 16 + ((ni >> 1) << 7);
        Cf[(long)row * ldc + col] = acc[mi][ni][j];
      }
}

// ---------------------------------------------------------------------------
// Flash attention, QBLK=128, 8 waves/block, 3-deep K/V ring + counted vmcnt.
// grid (4, B*H); each wave owns 16 q-rows.
// ---------------------------------------------------------------------------
template <int CAUSAL>
__global__ __launch_bounds__(512, 2) void fattn_k(
    const u16* __restrict__ Qg, const u16* __restrict__ Kg, const u16* __restrict__ Vtg,
    const int* __restrict__ qids, const int* __restrict__ kids, u16* __restrict__ ctx) {
  __shared__ u16 Qs[128 * 64];
  __shared__ u16 Ks[3][64 * 64];
  __shared__ u16 Vs[3][64 * 64];
  __shared__ u16 Ps[8][16 * 64];
  const int lane = threadIdx.x & 63, wid = threadIdx.x >> 6;  // wid 0..7
  const int qt = blockIdx.x, bh = blockIdx.y, b = bh >> 4, h = bh & 15;
  const int q0 = qt << 7;
  const u16* Qbase = Qg + ((long)bh * 512 + q0) * 64;
  const u16* Kbase = Kg + (long)bh * 512 * 64;
  const u16* Vbase = Vtg + (long)bh * 64 * 512;
  const int r8 = lane >> 3, sl = lane & 7;

#pragma unroll
  for (int c0 = 0; c0 < 16; c0 += 8) {
    int c = c0 + wid;
    int r = (c << 3) + r8;
    gld16(Qbase + (long)r * 64 + ((sl ^ (r & 7)) << 3), &Qs[c << 9]);
  }

  auto stageKV = [&](int buf, int kt) {
#pragma unroll
    for (int c0 = 0; c0 < 16; c0 += 8) {
      int c = c0 + wid;
      if (c < 8) {
        int r = (c << 3) + r8;
        gld16(Kbase + (long)(kt * 64 + r) * 64 + ((sl ^ (r & 7)) << 3), &Ks[buf][c << 9]);
      } else {
        int r = ((c - 8) << 3) + r8;
        gld16(Vbase + (long)r * 512 + kt * 64 + ((sl ^ (r & 7)) << 3), &Vs[buf][(c - 8) << 9]);
      }
    }
  };

  const int NKT = CAUSAL ? ((q0 >> 6) + 2) : 8;
  stageKV(0, 0);
  if (NKT > 1) stageKV(1, 1);
  if (NKT > 1) vwait<2>();
  else vwait<0>();
  __builtin_amdgcn_s_barrier();

  const f32x4 z4 = {0.f, 0.f, 0.f, 0.f};
  f32x4 oacc[4];
  float mrun[4], lrun[4];
  bool qv[4];
#pragma unroll
  for (int j = 0; j < 4; ++j) {
    mrun[j] = -3e38f;
    lrun[j] = 0.f;
    int qg = q0 + wid * 16 + ((lane >> 4) << 2) + j;
    qv[j] = qids[(b << 9) + qg] != 0;
  }
#pragma unroll
  for (int nd = 0; nd < 4; ++nd) oacc[nd] = z4;

  for (int kt = 0; kt < NKT; ++kt) {
    const int cur = kt % 3;
    if (kt + 2 < NKT) stageKV((kt + 2) % 3, kt + 2);
    f32x4 s[4];
#pragma unroll
    for (int n = 0; n < 4; ++n) s[n] = z4;
    __builtin_amdgcn_s_setprio(1);
#pragma unroll
    for (int kk = 0; kk < 2; ++kk) {
      bf16x8 aq, bk[4];
      int r = wid * 16 + (lane & 15);
      int slot = ((kk << 2) | (lane >> 4)) ^ (r & 7);
      aq = *(const bf16x8*)&Qs[(r << 6) + (slot << 3)];
#pragma unroll
      for (int n = 0; n < 4; ++n) {
        int c = n * 16 + (lane & 15);
        int slt = ((kk << 2) | (lane >> 4)) ^ (c & 7);
        bk[n] = *(const bf16x8*)&Ks[cur][(c << 6) + (slt << 3)];
      }
#pragma unroll
      for (int n = 0; n < 4; ++n)
        s[n] = __builtin_amdgcn_mfma_f32_16x16x32_bf16(aq, bk[n], s[n], 0, 0, 0);
    }
    __builtin_amdgcn_s_setprio(0);
    bool kvld[4];
#pragma unroll
    for (int n = 0; n < 4; ++n)
      kvld[n] = kids[(b << 9) + (kt << 6) + (n << 4) + (lane & 15)] != 0;
    float mx[4];
#pragma unroll
    for (int j = 0; j < 4; ++j) {
      mx[j] = -3e38f;
      int qg = q0 + wid * 16 + ((lane >> 4) << 2) + j;
#pragma unroll
      for (int n = 0; n < 4; ++n) {
        int colg = (kt << 6) + (n << 4) + (lane & 15);
        bool ok = qv[j] && kvld[n] && (!CAUSAL || colg <= qg);
        float sv = ok ? s[n][j] * 0.125f : -3e38f;
        s[n][j] = sv;
        mx[j] = fmaxf(mx[j], sv);
      }
      mx[j] = gmax16(mx[j]);
    }
    // online softmax; oacc[nd][j] is ROW j — rescale only component j.
#pragma unroll
    for (int j = 0; j < 4; ++j) {
      float mn = fmaxf(mrun[j], mx[j]);
      float f = __expf(mrun[j] - mn);
      mrun[j] = mn;
      float ps = 0.f;
#pragma unroll
      for (int n = 0; n < 4; ++n) {
        float sv = s[n][j];
        float p = (sv > -1e37f) ? __expf(sv - mn) : 0.f;
        s[n][j] = p;
        ps += p;
      }
      ps = gsum16(ps);
      lrun[j] = lrun[j] * f + ps;
#pragma unroll
      for (int nd = 0; nd < 4; ++nd) oacc[nd][j] *= f;
    }
#pragma unroll
    for (int n = 0; n < 4; ++n)
#pragma unroll
      for (int j = 0; j < 4; ++j) {
        int rl = ((lane >> 4) << 2) + j;
        int slot = ((n << 1) | ((lane >> 3) & 1)) ^ (rl & 7);
        Ps[wid][(rl << 6) + (slot << 3) + (lane & 7)] = f2bf(s[n][j]);
      }
    __builtin_amdgcn_s_setprio(1);
#pragma unroll
    for (int kk = 0; kk < 2; ++kk) {
      bf16x8 pa, vv[4];
      int r = lane & 15;
      int slot = ((kk << 2) | (lane >> 4)) ^ (r & 7);
      pa = *(const bf16x8*)&Ps[wid][(r << 6) + (slot << 3)];
#pragma unroll
      for (int nd = 0; nd < 4; ++nd) {
        int rv = (nd << 4) + (lane & 15);
        int slt = ((kk << 2) | (lane >> 4)) ^ (rv & 7);
        vv[nd] = *(const bf16x8*)&Vs[cur][(rv << 6) + (slt << 3)];
      }
#pragma unroll
      for (int nd = 0; nd < 4; ++nd)
        oacc[nd] = __builtin_amdgcn_mfma_f32_16x16x32_bf16(pa, vv[nd], oacc[nd], 0, 0, 0);
    }
    __builtin_amdgcn_s_setprio(0);
    const int ahead = NKT - 1 - kt;
    if (ahead >= 2) {
      vwait<2>();
      __builtin_amdgcn_s_barrier();
    } else if (ahead == 1) {
      vwait<0>();
      __builtin_amdgcn_s_barrier();
    }
  }
#pragma unroll
  for (int j = 0; j < 4; ++j) {
    float inv = (lrun[j] > 0.f) ? 1.0f / lrun[j] : 0.f;
    int qg = q0 + wid * 16 + ((lane >> 4) << 2) + j;
    long rowb = (((long)(b << 9) + qg) * 16 + h) * 64;
#pragma unroll
    for (int nd = 0; nd < 4; ++nd) {
      int d = (nd << 4) + (lane & 15);
      ctx[rowb + d] = f2bf(oacc[nd][j] * inv);
    }
  }
}

// ebf = bf16(emb[id]*32 + sinusoidal PE)
__global__ __launch_bounds__(256) void embed_k(const int* __restrict__ ids,
                                               const float* __restrict__ emb,
                                               u16* __restrict__ bfo) {
  const int tok = blockIdx.x, t = threadIdx.x;
  const int s = tok & 511;
  const long id = ids[tok];
  const int d = t * 4;
  float4 ev = *(const float4*)(emb + id * 1024 + d);
  float o[4] = {ev.x * 32.f, ev.y * 32.f, ev.z * 32.f, ev.w * 32.f};
#pragma unroll
  for (int j = 0; j < 4; ++j) {
    int dd = d + j, di = dd & 511;
    float ang = (float)s * expf(-(float)di * 0.0180241494559220821f);
    o[j] += (dd < 512) ? sinf(ang) : cosf(ang);
  }
  ushort4 ob = {f2bf(o[0]), f2bf(o[1]), f2bf(o[2]), f2bf(o[3])};
  *(ushort4*)(bfo + (long)tok * 1024 + d) = ob;
}

// ebf = bf16(LN(v)) where v (bf16) already holds x+sub (residual fused in GEMM)
__global__ __launch_bounds__(256) void ln_k(const u16* __restrict__ vin,
                                            const float* __restrict__ gam,
                                            const float* __restrict__ bet,
                                            u16* __restrict__ bfo) {
  __shared__ float red[8];
  const int row = blockIdx.x, t = threadIdx.x;
  const ushort4 xv = *(const ushort4*)(vin + (long)row * 1024 + t * 4);
  float v0 = bf2f(xv.x), v1 = bf2f(xv.y), v2 = bf2f(xv.z), v3 = bf2f(xv.w);
  float sm = wsum(v0 + v1 + v2 + v3);
  if ((t & 63) == 0) red[t >> 6] = sm;
  __syncthreads();
  const float mu = (red[0] + red[1] + red[2] + red[3]) * (1.0f / 1024.0f);
  const float d0 = v0 - mu, d1 = v1 - mu, d2 = v2 - mu, d3 = v3 - mu;
  float ss = wsum(d0 * d0 + d1 * d1 + d2 * d2 + d3 * d3);
  if ((t & 63) == 0) red[4 + (t >> 6)] = ss;
  __syncthreads();
  const float sig = sqrtf((red[4] + red[5] + red[6] + red[7]) * (1.0f / 1023.0f));
  const float inv = 1.0f / (sig + 0.001f);
  const float4 g4 = *(const float4*)(gam + t * 4);
  const float4 b4 = *(const float4*)(bet + t * 4);
  const float o0 = d0 * inv * g4.x + b4.x, o1 = d1 * inv * g4.y + b4.y;
  const float o2 = d2 * inv * g4.z + b4.z, o3 = d3 * inv * g4.w + b4.w;
  ushort4 ob = {f2bf(o0), f2bf(o1), f2bf(o2), f2bf(o3)};
  *(ushort4*)(bfo + (long)row * 1024 + t * 4) = ob;
}

__global__ void cvt_k(const float* __restrict__ src, u16* __restrict__ dst, int n4) {
  for (int i = blockIdx.x * 256 + threadIdx.x; i < n4; i += gridDim.x * 256) {
    float4 v = ((const float4*)src)[i];
    ushort4 o = {f2bf(v.x), f2bf(v.y), f2bf(v.z), f2bf(v.w)};
    ((ushort4*)dst)[i] = o;
  }
}

__global__ void cvt3_k(const float* __restrict__ s0, int n0, const float* __restrict__ s1,
                       int n1, const float* __restrict__ s2, int n2, u16* __restrict__ dst) {
  const int tot = n0 + n1 + n2;
  for (int i = blockIdx.x * 256 + threadIdx.x; i < tot; i += gridDim.x * 256) {
    const float* s;
    int j;
    if (i < n0) { s = s0; j = i; }
    else if (i < n0 + n1) { s = s1; j = i - n0; }
    else { s = s2; j = i - n0 - n1; }
    float4 v = ((const float4*)s)[j];
    ushort4 o = {f2bf(v.x), f2bf(v.y), f2bf(v.z), f2bf(v.w)};
    ((ushort4*)dst)[i] = o;
  }
}

extern "C" void kernel_launch(void* const* d_in, const int* in_sizes, int n_in, void* d_out,
                              int out_size, void* d_ws, size_t ws_size, hipStream_t stream) {
  (void)in_sizes; (void)n_in; (void)out_size;
  const float* emb_x = (const float*)d_in[0];
  const float* emb_y = (const float*)d_in[1];
  const float* enc_qkvo = (const float*)d_in[2];
  const float* enc_ln_s = (const float*)d_in[3];
  const float* enc_ln_b = (const float*)d_in[4];
  const float* enc_w1 = (const float*)d_in[5];
  const float* enc_b1 = (const float*)d_in[6];
  const float* enc_w2 = (const float*)d_in[7];
  const float* enc_b2 = (const float*)d_in[8];
  const float* dec_qkvo = (const float*)d_in[9];
  const float* dec_ln_s = (const float*)d_in[10];
  const float* dec_ln_b = (const float*)d_in[11];
  const float* dec_w1 = (const float*)d_in[12];
  const float* dec_b1 = (const float*)d_in[13];
  const float* dec_w2 = (const float*)d_in[14];
  const float* dec_b2 = (const float*)d_in[15];
  const int* x_block = (const int*)d_in[16];
  const int* y_block = (const int*)d_in[17];

  const long TOK = 2048, Dm = 1024, M1 = 1048576;
  char* p = (char*)d_ws;
  auto alloc = [&](long bytes) { char* r = p; p += (bytes + 255) & ~255L; return r; };
  u16* subb = (u16*)alloc(TOK * Dm * 2);
  u16* ebf = (u16*)alloc(TOK * Dm * 2);
  u16* zbf = (u16*)alloc(TOK * Dm * 2);
  u16* qb = (u16*)alloc(TOK * Dm * 2);
  u16* kb = (u16*)alloc(TOK * Dm * 2);
  u16* vtb = (u16*)alloc(TOK * Dm * 2);
  u16* ctx = (u16*)alloc(TOK * Dm * 2);
  u16* hbuf = (u16*)alloc(TOK * 4096 * 2);
  u16* embyb = (u16*)alloc(32000L * 1024 * 2);
  // weight arena: mega (all layers of one side at once, 96 M1) if ws allows,
  // else per-layer double-use buffer (16 M1).
  size_t used = (size_t)(p - (char*)d_ws);
  const bool mega = (used + 96L * M1 * 2 + 4096) <= ws_size;
  u16* wall = (u16*)alloc(mega ? 96L * M1 * 2 : 16L * M1 * 2);
  if ((size_t)(p - (char*)d_ws) > ws_size) return;

  auto gemmF = [&](const u16* A, const u16* Bw, int M, int N, int K, int lda, int ldb,
                   const float* bias, const u16* residb, u16* C, int ldc) {
    dim3 g(N / 64, M / 64);
    gemm_k<64, 64, 0, 2, 128><<<g, 256, 0, stream>>>(A, nullptr, Bw, lda, ldb, K, bias,
                                                     residb, ldc, C, nullptr, nullptr,
                                                     nullptr, 0);
  };
  auto gemmRelu = [&](const u16* A, const u16* Bw, const float* bias, u16* C) {
    dim3 g(32, 16);
    gemm_k<128, 128, 1, 2, 64><<<g, 256, 0, stream>>>(A, nullptr, Bw, 1024, 1024, 1024, bias,
                                                      nullptr, 4096, C, nullptr, nullptr,
                                                      nullptr, 0);
  };
  auto gemmQKV = [&](const u16* A, const u16* Bw) {  // N=3072, single A
    dim3 g(24, 32);
    gemm_k<64, 128, 2, 3, 64><<<g, 256, 0, stream>>>(A, nullptr, Bw, 1024, 1024, 1024,
                                                     nullptr, nullptr, 0, nullptr, qb, kb,
                                                     vtb, 0);
  };
  auto gemmQKVx = [&](const u16* Aq, const u16* Akv, const u16* Bw) {  // cross, N=3072
    dim3 g(24, 32);
    gemm_k<64, 128, 3, 3, 64><<<g, 256, 0, stream>>>(Aq, Akv, Bw, 1024, 1024, 1024,
                                                     nullptr, nullptr, 0, nullptr, qb, kb,
                                                     vtb, 0);
  };
  auto attn = [&](const int* qids, const int* kids, int causal) {
    if (causal)
      fattn_k<1><<<dim3(4, 64), 512, 0, stream>>>(qb, kb, vtb, qids, kids, ctx);
    else
      fattn_k<0><<<dim3(4, 64), 512, 0, stream>>>(qb, kb, vtb, qids, kids, ctx);
  };
  auto lnorm = [&](const float* g, const float* b) {
    ln_k<<<2048, 256, 0, stream>>>(subb, g, b, ebf);
  };

  cvt_k<<<2048, 256, 0, stream>>>(emb_y, embyb, 32000 * 1024 / 4);

  // ---------------- encoder ----------------
  embed_k<<<2048, 256, 0, stream>>>(x_block, emb_x, ebf);
  if (mega) {  // one conversion for all 6 enc layers: [qkvo x6][w1 x6][w2 x6]
    cvt3_k<<<2048, 256, 0, stream>>>(enc_qkvo, (int)(6 * M1), enc_w1, (int)(6 * M1),
                                     enc_w2, (int)(6 * M1), wall);
  }
  for (int i = 0; i < 6; ++i) {
    u16 *Wqkvo, *Ww1, *Ww2;
    if (mega) {
      Wqkvo = wall + (long)i * 4 * M1;
      Ww1 = wall + 24L * M1 + (long)i * 4 * M1;
      Ww2 = wall + 48L * M1 + (long)i * 4 * M1;
    } else {
      cvt3_k<<<2048, 256, 0, stream>>>(enc_qkvo + (long)i * 4 * M1, (int)M1,
                                       enc_w1 + (long)i * 4 * M1, (int)M1,
                                       enc_w2 + (long)i * 4 * M1, (int)M1, wall);
      Wqkvo = wall;
      Ww1 = wall + 4L * M1;
      Ww2 = wall + 8L * M1;
    }
    gemmQKV(ebf, Wqkvo);
    attn(x_block, x_block, 0);
    gemmF(ctx, Wqkvo + 3L * M1, 2048, 1024, 1024, 1024, 1024, nullptr, ebf, subb, 1024);
    lnorm(enc_ln_s + (i * 2 + 0) * 1024, enc_ln_b + (i * 2 + 0) * 1024);
    gemmRelu(ebf, Ww1, enc_b1 + i * 4096, hbuf);
    gemmF(hbuf, Ww2, 2048, 1024, 4096, 4096, 4096, enc_b2 + i * 1024, ebf, subb, 1024);
    lnorm(enc_ln_s + (i * 2 + 1) * 1024, enc_ln_b + (i * 2 + 1) * 1024);
  }
  hipMemcpyAsync(zbf, ebf, TOK * Dm * 2, hipMemcpyDeviceToDevice, stream);

  // ---------------- decoder ----------------
  embed_k<<<2048, 256, 0, stream>>>(y_block, emb_y, ebf);
  if (mega) {  // [qkvo x6 (8 M1 each)][w1 x6][w2 x6]
    cvt3_k<<<2048, 256, 0, stream>>>(dec_qkvo, (int)(12 * M1), dec_w1, (int)(6 * M1),
                                     dec_w2, (int)(6 * M1), wall);
  }
  for (int i = 0; i < 6; ++i) {
    u16 *Wqkvo, *Ww1, *Ww2;
    if (mega) {
      Wqkvo = wall + (long)i * 8 * M1;
      Ww1 = wall + 48L * M1 + (long)i * 4 * M1;
      Ww2 = wall + 72L * M1 + (long)i * 4 * M1;
    } else {
      cvt3_k<<<2048, 256, 0, stream>>>(dec_qkvo + (long)i * 8 * M1, (int)(2 * M1),
                                       dec_w1 + (long)i * 4 * M1, (int)M1,
                                       dec_w2 + (long)i * 4 * M1, (int)M1, wall);
      Wqkvo = wall;
      Ww1 = wall + 8L * M1;
      Ww2 = wall + 12L * M1;
    }
    // self-attention (causal)
    gemmQKV(ebf, Wqkvo);
    attn(y_block, y_block, 1);
    gemmF(ctx, Wqkvo + 3L * M1, 2048, 1024, 1024, 1024, 1024, nullptr, ebf, subb, 1024);
    lnorm(dec_ln_s + (i * 3 + 0) * 1024, dec_ln_b + (i * 3 + 0) * 1024);
    // cross-attention: Q from ebf, K/V from zbf, one merged dispatch
    gemmQKVx(ebf, zbf, Wqkvo + 4L * M1);
    attn(y_block, x_block, 0);
    gemmF(ctx, Wqkvo + 7L * M1, 2048, 1024, 1024, 1024, 1024, nullptr, ebf, subb, 1024);
    lnorm(dec_ln_s + (i * 3 + 1) * 1024, dec_ln_b + (i * 3 + 1) * 1024);
    // ffn
    gemmRelu(ebf, Ww1, dec_b1 + i * 4096, hbuf);
    gemmF(hbuf, Ww2, 2048, 1024, 4096, 4096, 4096, dec_b2 + i * 1024, ebf, subb, 1024);
    lnorm(dec_ln_s + (i * 3 + 2) * 1024, dec_ln_b + (i * 3 + 2) * 1024);
  }
  // final vocab projection -> d_out fp32 [B*SY, 32000] via 256^2 4-phase GEMM
  gemm256_k<<<dim3(125, 8), 512, 0, stream>>>(ebf, embyb, 1024, 1024, 1024,
                                              (float*)d_out, 32000);
}

// Round 15
// 2156.401 us; speedup vs baseline: 1.0964x; 1.0964x over previous
//
#include <hip/hip_runtime.h>

typedef unsigned short u16;
typedef float f32x4 __attribute__((ext_vector_type(4)));
typedef __bf16 bf16x8 __attribute__((ext_vector_type(8)));
typedef u16 u16x8 __attribute__((ext_vector_type(8)));

#define DEV __device__ __forceinline__

DEV u16 f2bf(float f) {
  unsigned u = __builtin_bit_cast(unsigned, f);
  u += 0x7fffu + ((u >> 16) & 1u);
  return (u16)(u >> 16);
}
DEV float bf2f(u16 b) { return __builtin_bit_cast(float, (unsigned)b << 16); }

DEV float wsum(float v) {
#pragma unroll
  for (int o = 32; o > 0; o >>= 1) v += __shfl_xor(v, o, 64);
  return v;
}
DEV float gmax16(float v) {
#pragma unroll
  for (int o = 8; o > 0; o >>= 1) v = fmaxf(v, __shfl_xor(v, o, 64));
  return v;
}
DEV float gsum16(float v) {
#pragma unroll
  for (int o = 8; o > 0; o >>= 1) v += __shfl_xor(v, o, 64);
  return v;
}

DEV void gld16(const void* g, void* l) {
  __builtin_amdgcn_global_load_lds((const __attribute__((address_space(1))) void*)g,
                                   (__attribute__((address_space(3))) void*)l, 16, 0, 0);
}

template <int N>
DEV void vwait() {
  if constexpr (N == 0) asm volatile("s_waitcnt vmcnt(0)" ::: "memory");
  else if constexpr (N == 2) asm volatile("s_waitcnt vmcnt(2)" ::: "memory");
  else if constexpr (N == 4) asm volatile("s_waitcnt vmcnt(4)" ::: "memory");
  else asm volatile("s_waitcnt vmcnt(6)" ::: "memory");
}

// M-major within N + bijective XCD-chunked swizzle.
DEV void remap_bxy(int& bx, int& by) {
  const int gx = gridDim.x, gy = gridDim.y;
  const int flat = blockIdx.y * gx + blockIdx.x;
  const int nwg = gx * gy;
  const int q = nwg >> 3, r = nwg & 7;
  const int xcd = flat & 7, li = flat >> 3;
  const int wg = (xcd < r ? xcd * (q + 1) : r * (q + 1) + (xcd - r) * q) + li;
  by = wg % gy;  // M tile (inner)
  bx = wg / gy;  // N tile (outer)
}

// ---------------------------------------------------------------------------
// NT GEMM (2-barrier, BK = 64 or 128). W = blocks/CU.
// MODE 0: Cb = bf16(acc (+bias[col]) (+bf16 resid[row][col]))   (bf16 out)
// MODE 1: Cb = bf16(relu(acc + bias[col]))                      (ffn1)
// MODE 2: scatter bf16 q/k -> [B,H,S,DK]; V -> LDS-transposed [B,H,DK,S]
// MODE 3: like MODE 2 but dual-A: cols >= 1024 read A2 (cross-attn merge)
// ---------------------------------------------------------------------------
template <int BM, int BN, int MODE, int W, int BK>
__global__ __launch_bounds__(256, W) void gemm_k(
    const u16* __restrict__ A, const u16* __restrict__ A2,
    const u16* __restrict__ B, int lda, int ldb, int K,
    const float* __restrict__ bias, const u16* __restrict__ residb,
    int ldc, u16* __restrict__ Cb, u16* __restrict__ qp,
    u16* __restrict__ kp, u16* __restrict__ vp, int n_off) {
  constexpr int FM = BM / 32, FN = BN / 32;
  constexpr int CHA = BM / 8, CHT = (BM + BN) / 8;
  constexpr int KCH = BK / 64;
  __shared__ u16 lds[2][(BM + BN) * BK];
  const int lane = threadIdx.x & 63, wid = threadIdx.x >> 6;
  const int wr = wid >> 1, wc = wid & 1;
  int bx, by;
  remap_bxy(bx, by);
  const u16* Abase = A;
  if constexpr (MODE == 3) {
    if (bx * BN >= 1024) Abase = A2;
  }
  const u16* gA = Abase + (long)(by * BM) * lda;
  const u16* gB = B + (long)(bx * BN) * ldb;

  const f32x4 zero4 = {0.f, 0.f, 0.f, 0.f};
  f32x4 acc[FM][FN];
#pragma unroll
  for (int m = 0; m < FM; ++m)
#pragma unroll
    for (int n = 0; n < FN; ++n) acc[m][n] = zero4;

  const int r8 = lane >> 3, sl = lane & 7;

  auto stage = [&](int buf, int kt) {
#pragma unroll
    for (int sub = 0; sub < KCH; ++sub) {
      const int kb = kt * BK + (sub << 6);
      u16* lbase = &lds[buf][sub * (BM + BN) * 64];
#pragma unroll
      for (int c0 = 0; c0 < CHT; c0 += 4) {
        const int c = c0 + wid;
        u16* l = lbase + (c << 9);
        const u16* g;
        if (c < CHA) {
          int r = (c << 3) + r8;
          g = gA + (long)r * lda + kb + ((sl ^ (r & 7)) << 3);
        } else {
          int r = ((c - CHA) << 3) + r8;
          g = gB + (long)r * ldb + kb + ((sl ^ (r & 7)) << 3);
        }
        gld16(g, l);
      }
    }
  };

  const int KT = K / BK;
  stage(0, 0);
  __syncthreads();
  int cur = 0;
  for (int kt = 0; kt < KT; ++kt) {
    if (kt + 1 < KT) stage(cur ^ 1, kt + 1);
#pragma unroll
    for (int q = 0; q < 2 * KCH; ++q) {
      const int kh = q >> 1, kl = q & 1;
      const u16* lA = &lds[cur][kh * (BM + BN) * 64];
      const u16* lB = lA + (BM << 6);
      bf16x8 af[FM], bv[FN];
#pragma unroll
      for (int m = 0; m < FM; ++m) {
        int r = wr * (BM / 2) + m * 16 + (lane & 15);
        int slot = ((kl << 2) | (lane >> 4)) ^ (r & 7);
        af[m] = *(const bf16x8*)(lA + (r << 6) + (slot << 3));
      }
#pragma unroll
      for (int n = 0; n < FN; ++n) {
        int r = wc * (BN / 2) + n * 16 + (lane & 15);
        int slot = ((kl << 2) | (lane >> 4)) ^ (r & 7);
        bv[n] = *(const bf16x8*)(lB + (r << 6) + (slot << 3));
      }
#pragma unroll
      for (int m = 0; m < FM; ++m)
#pragma unroll
        for (int n = 0; n < FN; ++n)
          acc[m][n] = __builtin_amdgcn_mfma_f32_16x16x32_bf16(af[m], bv[n], acc[m][n], 0, 0, 0);
    }
    __syncthreads();
    cur ^= 1;
  }

  const int rb = by * BM + wr * (BM / 2) + ((lane >> 4) << 2);
  const int cb = bx * BN + wc * (BN / 2) + (lane & 15);
  if constexpr (MODE == 2 || MODE == 3) {
    const bool isV = (bx * BN + n_off) >= 2048;
    if (isV) {
      __syncthreads();
      u16* T = (u16*)&lds[0][0];  // [BN][BM+8]
      constexpr int TS = BM + 8;
#pragma unroll
      for (int m = 0; m < FM; ++m)
#pragma unroll
        for (int n = 0; n < FN; ++n) {
          int cl = wc * (BN / 2) + n * 16 + (lane & 15);
#pragma unroll
          for (int j = 0; j < 4; ++j) {
            int rl = wr * (BM / 2) + m * 16 + ((lane >> 4) << 2) + j;
            T[cl * TS + rl] = f2bf(acc[m][n][j]);
          }
        }
      __syncthreads();
      const int vcb = bx * BN + n_off - 2048;
      const int b = (by * BM) >> 9, s0 = (by * BM) & 511;
#pragma unroll
      for (int p = 0; p < BM * BN / 2048; ++p) {
        int idx = p * 2048 + threadIdx.x * 8;
        int dl = idx / BM, slx = idx & (BM - 1);
        u16x8 o;
#pragma unroll
        for (int e = 0; e < 8; ++e) o[e] = T[dl * TS + slx + e];
        int vc = vcb + dl;
        *(u16x8*)(vp + (((long)b * 16 + (vc >> 6)) * 64 + (vc & 63)) * 512 + s0 + slx) = o;
      }
    } else {
#pragma unroll
      for (int m = 0; m < FM; ++m)
#pragma unroll
        for (int n = 0; n < FN; ++n)
#pragma unroll
          for (int j = 0; j < 4; ++j) {
            const int row = rb + m * 16 + j;
            const int np = cb + n * 16 + n_off;
            const int sel = np >> 10, dim = np & 1023;
            long base = (((long)(row >> 9) * 16 + (dim >> 6)) * 512 + (row & 511)) * 64 + (dim & 63);
            u16 val = f2bf(acc[m][n][j]);
            if (sel == 0) qp[base] = val;
            else kp[base] = val;
          }
    }
  } else {
#pragma unroll
    for (int m = 0; m < FM; ++m)
#pragma unroll
      for (int n = 0; n < FN; ++n)
#pragma unroll
        for (int j = 0; j < 4; ++j) {
          const int row = rb + m * 16 + j;
          const int col = cb + n * 16;
          float v = acc[m][n][j];
          if constexpr (MODE == 0) {
            if (bias) v += bias[col];
            if (residb) v += bf2f(residb[(long)row * ldc + col]);
            Cb[(long)row * ldc + col] = f2bf(v);
          } else {
            Cb[(long)row * ldc + col] = f2bf(fmaxf(v + bias[col], 0.f));
          }
        }
  }
}

// ---------------------------------------------------------------------------
// 256x256 8-wave deep-pipelined NT GEMM (vocab projection) — R5 schedule.
// ---------------------------------------------------------------------------
__global__ __launch_bounds__(512, 1) void gemm256_k(
    const u16* __restrict__ A, const u16* __restrict__ B, int lda, int ldb, int K,
    float* __restrict__ Cf, int ldc) {
  __shared__ u16 As[2][256 * 64];
  __shared__ u16 Bs[2][256 * 64];
  const int lane = threadIdx.x & 63, wid = threadIdx.x >> 6;
  const int wr = wid >> 2, wc = wid & 3;  // 2M x 4N waves
  int bx, by;
  remap_bxy(bx, by);
  const u16* gA = A + (long)(by * 256) * lda;
  const u16* gB = B + (long)(bx * 256) * ldb;

  const f32x4 z4 = {0.f, 0.f, 0.f, 0.f};
  f32x4 acc[8][4];
#pragma unroll
  for (int m = 0; m < 8; ++m)
#pragma unroll
    for (int n = 0; n < 4; ++n) acc[m][n] = z4;

  const int ssl = lane & 7;

  auto stageH = [&](int t, int h) {
    const int kb = t << 6;
    const int buf = t & 1;
    const bool isA = (h == 0) || (h == 3);
    u16* ldsb = isA ? &As[buf][0] : &Bs[buf][0];
    const u16* gsrc = isA ? gA : gB;
    const int ld = isA ? lda : ldb;
    const int rbase = (h >= 2) ? 128 : 0;
#pragma unroll
    for (int rr = 0; rr < 2; ++rr) {
      const int r0 = rbase + rr * 64 + (wid << 3);
      const int r = r0 + (lane >> 3);
      gld16(gsrc + (long)r * ld + kb + ((ssl ^ (r & 7)) << 3), ldsb + (r0 << 6));
    }
  };

  const int KT = K >> 6;
  stageH(0, 0);
  stageH(0, 1);
  stageH(0, 2);
  stageH(0, 3);

  for (int t = 0; t < KT; ++t) {
    const int buf = t & 1;
    const bool more = (t + 1 < KT);
    const u16* lA = &As[buf][0];
    const u16* lB = &Bs[buf][0];
    bf16x8 af[4][2], bvl[2][2], bvh[2][2];

    // ---- phase 0: mlo x nlo
    vwait<4>();
    __builtin_amdgcn_s_barrier();
    __builtin_amdgcn_sched_barrier(0);
#pragma unroll
    for (int m = 0; m < 4; ++m)
#pragma unroll
      for (int kk = 0; kk < 2; ++kk) {
        int r = wr * 64 + m * 16 + (lane & 15);
        int sg = ((kk << 2) | (lane >> 4)) ^ (r & 7);
        af[m][kk] = *(const bf16x8*)(lA + (r << 6) + (sg << 3));
      }
#pragma unroll
    for (int n = 0; n < 2; ++n)
#pragma unroll
      for (int kk = 0; kk < 2; ++kk) {
        int c = wc * 32 + n * 16 + (lane & 15);
        int sg = ((kk << 2) | (lane >> 4)) ^ (c & 7);
        bvl[n][kk] = *(const bf16x8*)(lB + (c << 6) + (sg << 3));
      }
    if (more) stageH(t + 1, 0);
    __builtin_amdgcn_s_setprio(1);
#pragma unroll
    for (int kk = 0; kk < 2; ++kk)
#pragma unroll
      for (int m = 0; m < 4; ++m)
#pragma unroll
        for (int n = 0; n < 2; ++n)
          acc[m][n] = __builtin_amdgcn_mfma_f32_16x16x32_bf16(af[m][kk], bvl[n][kk], acc[m][n], 0, 0, 0);
    __builtin_amdgcn_s_setprio(0);

    // ---- phase 1: mlo x nhi
    if (more) vwait<4>();
    else vwait<2>();
    __builtin_amdgcn_s_barrier();
    __builtin_amdgcn_sched_barrier(0);
#pragma unroll
    for (int n = 0; n < 2; ++n)
#pragma unroll
      for (int kk = 0; kk < 2; ++kk) {
        int c = 128 + wc * 32 + n * 16 + (lane & 15);
        int sg = ((kk << 2) | (lane >> 4)) ^ (c & 7);
        bvh[n][kk] = *(const bf16x8*)(lB + (c << 6) + (sg << 3));
      }
    if (more) stageH(t + 1, 1);
    __builtin_amdgcn_s_setprio(1);
#pragma unroll
    for (int kk = 0; kk < 2; ++kk)
#pragma unroll
      for (int m = 0; m < 4; ++m)
#pragma unroll
        for (int n = 0; n < 2; ++n)
          acc[m][2 + n] = __builtin_amdgcn_mfma_f32_16x16x32_bf16(af[m][kk], bvh[n][kk], acc[m][2 + n], 0, 0, 0);
    __builtin_amdgcn_s_setprio(0);

    // ---- phase 2: mhi x nhi
    if (more) vwait<4>();
    else vwait<0>();
    __builtin_amdgcn_s_barrier();
    __builtin_amdgcn_sched_barrier(0);
#pragma unroll
    for (int m = 0; m < 4; ++m)
#pragma unroll
      for (int kk = 0; kk < 2; ++kk) {
        int r = 128 + wr * 64 + m * 16 + (lane & 15);
        int sg = ((kk << 2) | (lane >> 4)) ^ (r & 7);
        af[m][kk] = *(const bf16x8*)(lA + (r << 6) + (sg << 3));
      }
    if (more) stageH(t + 1, 2);
    __builtin_amdgcn_s_setprio(1);
#pragma unroll
    for (int kk = 0; kk < 2; ++kk)
#pragma unroll
      for (int m = 0; m < 4; ++m)
#pragma unroll
        for (int n = 0; n < 2; ++n)
          acc[4 + m][2 + n] = __builtin_amdgcn_mfma_f32_16x16x32_bf16(af[m][kk], bvh[n][kk], acc[4 + m][2 + n], 0, 0, 0);
    __builtin_amdgcn_s_setprio(0);

    // ---- phase 3: mhi x nlo
    __builtin_amdgcn_s_barrier();
    __builtin_amdgcn_sched_barrier(0);
    if (more) stageH(t + 1, 3);
    __builtin_amdgcn_s_setprio(1);
#pragma unroll
    for (int kk = 0; kk < 2; ++kk)
#pragma unroll
      for (int m = 0; m < 4; ++m)
#pragma unroll
        for (int n = 0; n < 2; ++n)
          acc[4 + m][n] = __builtin_amdgcn_mfma_f32_16x16x32_bf16(af[m][kk], bvl[n][kk], acc[4 + m][n], 0, 0, 0);
    __builtin_amdgcn_s_setprio(0);
  }

  const int rb = by * 256 + wr * 64 + ((lane >> 4) << 2);
  const int cb = bx * 256 + wc * 32 + (lane & 15);
#pragma unroll
  for (int mi = 0; mi < 8; ++mi)
#pragma unroll
    for (int ni = 0; ni < 4; ++ni)
#pragma unroll
      for (int j = 0; j < 4; ++j) {
        int row = rb + (mi & 3) * 16 + ((mi >> 2) << 7) + j;
        int col = cb + (ni & 1) * 16 + ((ni >> 1) << 7);
        Cf[(long)row * ldc + col] = acc[mi][ni][j];
      }
}

// ---------------------------------------------------------------------------
// Flash attention, QBLK=128, 8 waves/block, 3-deep K/V ring + counted vmcnt.
// grid (4, B*H); each wave owns 16 q-rows.
// ---------------------------------------------------------------------------
template <int CAUSAL>
__global__ __launch_bounds__(512, 2) void fattn_k(
    const u16* __restrict__ Qg, const u16* __restrict__ Kg, const u16* __restrict__ Vtg,
    const int* __restrict__ qids, const int* __restrict__ kids, u16* __restrict__ ctx) {
  __shared__ u16 Qs[128 * 64];
  __shared__ u16 Ks[3][64 * 64];
  __shared__ u16 Vs[3][64 * 64];
  __shared__ u16 Ps[8][16 * 64];
  const int lane = threadIdx.x & 63, wid = threadIdx.x >> 6;  // wid 0..7
  const int qt = blockIdx.x, bh = blockIdx.y, b = bh >> 4, h = bh & 15;
  const int q0 = qt << 7;
  const u16* Qbase = Qg + ((long)bh * 512 + q0) * 64;
  const u16* Kbase = Kg + (long)bh * 512 * 64;
  const u16* Vbase = Vtg + (long)bh * 64 * 512;
  const int r8 = lane >> 3, sl = lane & 7;

#pragma unroll
  for (int c0 = 0; c0 < 16; c0 += 8) {
    int c = c0 + wid;
    int r = (c << 3) + r8;
    gld16(Qbase + (long)r * 64 + ((sl ^ (r & 7)) << 3), &Qs[c << 9]);
  }

  auto stageKV = [&](int buf, int kt) {
#pragma unroll
    for (int c0 = 0; c0 < 16; c0 += 8) {
      int c = c0 + wid;
      if (c < 8) {
        int r = (c << 3) + r8;
        gld16(Kbase + (long)(kt * 64 + r) * 64 + ((sl ^ (r & 7)) << 3), &Ks[buf][c << 9]);
      } else {
        int r = ((c - 8) << 3) + r8;
        gld16(Vbase + (long)r * 512 + kt * 64 + ((sl ^ (r & 7)) << 3), &Vs[buf][(c - 8) << 9]);
      }
    }
  };

  const int NKT = CAUSAL ? ((q0 >> 6) + 2) : 8;
  stageKV(0, 0);
  if (NKT > 1) stageKV(1, 1);
  if (NKT > 1) vwait<2>();
  else vwait<0>();
  __builtin_amdgcn_s_barrier();

  const f32x4 z4 = {0.f, 0.f, 0.f, 0.f};
  f32x4 oacc[4];
  float mrun[4], lrun[4];
  bool qv[4];
#pragma unroll
  for (int j = 0; j < 4; ++j) {
    mrun[j] = -3e38f;
    lrun[j] = 0.f;
    int qg = q0 + wid * 16 + ((lane >> 4) << 2) + j;
    qv[j] = qids[(b << 9) + qg] != 0;
  }
#pragma unroll
  for (int nd = 0; nd < 4; ++nd) oacc[nd] = z4;

  for (int kt = 0; kt < NKT; ++kt) {
    const int cur = kt % 3;
    if (kt + 2 < NKT) stageKV((kt + 2) % 3, kt + 2);
    f32x4 s[4];
#pragma unroll
    for (int n = 0; n < 4; ++n) s[n] = z4;
    __builtin_amdgcn_s_setprio(1);
#pragma unroll
    for (int kk = 0; kk < 2; ++kk) {
      bf16x8 aq, bk[4];
      int r = wid * 16 + (lane & 15);
      int slot = ((kk << 2) | (lane >> 4)) ^ (r & 7);
      aq = *(const bf16x8*)&Qs[(r << 6) + (slot << 3)];
#pragma unroll
      for (int n = 0; n < 4; ++n) {
        int c = n * 16 + (lane & 15);
        int slt = ((kk << 2) | (lane >> 4)) ^ (c & 7);
        bk[n] = *(const bf16x8*)&Ks[cur][(c << 6) + (slt << 3)];
      }
#pragma unroll
      for (int n = 0; n < 4; ++n)
        s[n] = __builtin_amdgcn_mfma_f32_16x16x32_bf16(aq, bk[n], s[n], 0, 0, 0);
    }
    __builtin_amdgcn_s_setprio(0);
    bool kvld[4];
#pragma unroll
    for (int n = 0; n < 4; ++n)
      kvld[n] = kids[(b << 9) + (kt << 6) + (n << 4) + (lane & 15)] != 0;
    float mx[4];
#pragma unroll
    for (int j = 0; j < 4; ++j) {
      mx[j] = -3e38f;
      int qg = q0 + wid * 16 + ((lane >> 4) << 2) + j;
#pragma unroll
      for (int n = 0; n < 4; ++n) {
        int colg = (kt << 6) + (n << 4) + (lane & 15);
        bool ok = qv[j] && kvld[n] && (!CAUSAL || colg <= qg);
        float sv = ok ? s[n][j] * 0.125f : -3e38f;
        s[n][j] = sv;
        mx[j] = fmaxf(mx[j], sv);
      }
      mx[j] = gmax16(mx[j]);
    }
    // online softmax; oacc[nd][j] is ROW j — rescale only component j.
#pragma unroll
    for (int j = 0; j < 4; ++j) {
      float mn = fmaxf(mrun[j], mx[j]);
      float f = __expf(mrun[j] - mn);
      mrun[j] = mn;
      float ps = 0.f;
#pragma unroll
      for (int n = 0; n < 4; ++n) {
        float sv = s[n][j];
        float p = (sv > -1e37f) ? __expf(sv - mn) : 0.f;
        s[n][j] = p;
        ps += p;
      }
      ps = gsum16(ps);
      lrun[j] = lrun[j] * f + ps;
#pragma unroll
      for (int nd = 0; nd < 4; ++nd) oacc[nd][j] *= f;
    }
#pragma unroll
    for (int n = 0; n < 4; ++n)
#pragma unroll
      for (int j = 0; j < 4; ++j) {
        int rl = ((lane >> 4) << 2) + j;
        int slot = ((n << 1) | ((lane >> 3) & 1)) ^ (rl & 7);
        Ps[wid][(rl << 6) + (slot << 3) + (lane & 7)] = f2bf(s[n][j]);
      }
    __builtin_amdgcn_s_setprio(1);
#pragma unroll
    for (int kk = 0; kk < 2; ++kk) {
      bf16x8 pa, vv[4];
      int r = lane & 15;
      int slot = ((kk << 2) | (lane >> 4)) ^ (r & 7);
      pa = *(const bf16x8*)&Ps[wid][(r << 6) + (slot << 3)];
#pragma unroll
      for (int nd = 0; nd < 4; ++nd) {
        int rv = (nd << 4) + (lane & 15);
        int slt = ((kk << 2) | (lane >> 4)) ^ (rv & 7);
        vv[nd] = *(const bf16x8*)&Vs[cur][(rv << 6) + (slt << 3)];
      }
#pragma unroll
      for (int nd = 0; nd < 4; ++nd)
        oacc[nd] = __builtin_amdgcn_mfma_f32_16x16x32_bf16(pa, vv[nd], oacc[nd], 0, 0, 0);
    }
    __builtin_amdgcn_s_setprio(0);
    const int ahead = NKT - 1 - kt;
    if (ahead >= 2) {
      vwait<2>();
      __builtin_amdgcn_s_barrier();
    } else if (ahead == 1) {
      vwait<0>();
      __builtin_amdgcn_s_barrier();
    }
  }
#pragma unroll
  for (int j = 0; j < 4; ++j) {
    float inv = (lrun[j] > 0.f) ? 1.0f / lrun[j] : 0.f;
    int qg = q0 + wid * 16 + ((lane >> 4) << 2) + j;
    long rowb = (((long)(b << 9) + qg) * 16 + h) * 64;
#pragma unroll
    for (int nd = 0; nd < 4; ++nd) {
      int d = (nd << 4) + (lane & 15);
      ctx[rowb + d] = f2bf(oacc[nd][j] * inv);
    }
  }
}

// ebf = bf16(emb[id]*32 + sinusoidal PE)
__global__ __launch_bounds__(256) void embed_k(const int* __restrict__ ids,
                                               const float* __restrict__ emb,
                                               u16* __restrict__ bfo) {
  const int tok = blockIdx.x, t = threadIdx.x;
  const int s = tok & 511;
  const long id = ids[tok];
  const int d = t * 4;
  float4 ev = *(const float4*)(emb + id * 1024 + d);
  float o[4] = {ev.x * 32.f, ev.y * 32.f, ev.z * 32.f, ev.w * 32.f};
#pragma unroll
  for (int j = 0; j < 4; ++j) {
    int dd = d + j, di = dd & 511;
    float ang = (float)s * expf(-(float)di * 0.0180241494559220821f);
    o[j] += (dd < 512) ? sinf(ang) : cosf(ang);
  }
  ushort4 ob = {f2bf(o[0]), f2bf(o[1]), f2bf(o[2]), f2bf(o[3])};
  *(ushort4*)(bfo + (long)tok * 1024 + d) = ob;
}

// ebf = bf16(LN(v)) where v (bf16) already holds x+sub (residual fused in GEMM)
__global__ __launch_bounds__(256) void ln_k(const u16* __restrict__ vin,
                                            const float* __restrict__ gam,
                                            const float* __restrict__ bet,
                                            u16* __restrict__ bfo) {
  __shared__ float red[8];
  const int row = blockIdx.x, t = threadIdx.x;
  const ushort4 xv = *(const ushort4*)(vin + (long)row * 1024 + t * 4);
  float v0 = bf2f(xv.x), v1 = bf2f(xv.y), v2 = bf2f(xv.z), v3 = bf2f(xv.w);
  float sm = wsum(v0 + v1 + v2 + v3);
  if ((t & 63) == 0) red[t >> 6] = sm;
  __syncthreads();
  const float mu = (red[0] + red[1] + red[2] + red[3]) * (1.0f / 1024.0f);
  const float d0 = v0 - mu, d1 = v1 - mu, d2 = v2 - mu, d3 = v3 - mu;
  float ss = wsum(d0 * d0 + d1 * d1 + d2 * d2 + d3 * d3);
  if ((t & 63) == 0) red[4 + (t >> 6)] = ss;
  __syncthreads();
  const float sig = sqrtf((red[4] + red[5] + red[6] + red[7]) * (1.0f / 1023.0f));
  const float inv = 1.0f / (sig + 0.001f);
  const float4 g4 = *(const float4*)(gam + t * 4);
  const float4 b4 = *(const float4*)(bet + t * 4);
  const float o0 = d0 * inv * g4.x + b4.x, o1 = d1 * inv * g4.y + b4.y;
  const float o2 = d2 * inv * g4.z + b4.z, o3 = d3 * inv * g4.w + b4.w;
  ushort4 ob = {f2bf(o0), f2bf(o1), f2bf(o2), f2bf(o3)};
  *(ushort4*)(bfo + (long)row * 1024 + t * 4) = ob;
}

__global__ void cvt_k(const float* __restrict__ src, u16* __restrict__ dst, int n4) {
  for (int i = blockIdx.x * 256 + threadIdx.x; i < n4; i += gridDim.x * 256) {
    float4 v = ((const float4*)src)[i];
    ushort4 o = {f2bf(v.x), f2bf(v.y), f2bf(v.z), f2bf(v.w)};
    ((ushort4*)dst)[i] = o;
  }
}

__global__ void cvt3_k(const float* __restrict__ s0, int n0, const float* __restrict__ s1,
                       int n1, const float* __restrict__ s2, int n2, u16* __restrict__ dst) {
  const int tot = n0 + n1 + n2;
  for (int i = blockIdx.x * 256 + threadIdx.x; i < tot; i += gridDim.x * 256) {
    const float* s;
    int j;
    if (i < n0) { s = s0; j = i; }
    else if (i < n0 + n1) { s = s1; j = i - n0; }
    else { s = s2; j = i - n0 - n1; }
    float4 v = ((const float4*)s)[j];
    ushort4 o = {f2bf(v.x), f2bf(v.y), f2bf(v.z), f2bf(v.w)};
    ((ushort4*)dst)[i] = o;
  }
}

extern "C" void kernel_launch(void* const* d_in, const int* in_sizes, int n_in, void* d_out,
                              int out_size, void* d_ws, size_t ws_size, hipStream_t stream) {
  (void)in_sizes; (void)n_in; (void)out_size;
  const float* emb_x = (const float*)d_in[0];
  const float* emb_y = (const float*)d_in[1];
  const float* enc_qkvo = (const float*)d_in[2];
  const float* enc_ln_s = (const float*)d_in[3];
  const float* enc_ln_b = (const float*)d_in[4];
  const float* enc_w1 = (const float*)d_in[5];
  const float* enc_b1 = (const float*)d_in[6];
  const float* enc_w2 = (const float*)d_in[7];
  const float* enc_b2 = (const float*)d_in[8];
  const float* dec_qkvo = (const float*)d_in[9];
  const float* dec_ln_s = (const float*)d_in[10];
  const float* dec_ln_b = (const float*)d_in[11];
  const float* dec_w1 = (const float*)d_in[12];
  const float* dec_b1 = (const float*)d_in[13];
  const float* dec_w2 = (const float*)d_in[14];
  const float* dec_b2 = (const float*)d_in[15];
  const int* x_block = (const int*)d_in[16];
  const int* y_block = (const int*)d_in[17];

  const long TOK = 2048, Dm = 1024, M1 = 1048576;
  char* p = (char*)d_ws;
  auto alloc = [&](long bytes) { char* r = p; p += (bytes + 255) & ~255L; return r; };
  u16* subb = (u16*)alloc(TOK * Dm * 2);
  u16* ebf = (u16*)alloc(TOK * Dm * 2);
  u16* zbf = (u16*)alloc(TOK * Dm * 2);
  u16* qb = (u16*)alloc(TOK * Dm * 2);
  u16* kb = (u16*)alloc(TOK * Dm * 2);
  u16* vtb = (u16*)alloc(TOK * Dm * 2);
  u16* ctx = (u16*)alloc(TOK * Dm * 2);
  u16* hbuf = (u16*)alloc(TOK * 4096 * 2);
  u16* wbuf = (u16*)alloc(16L * M1 * 2);
  u16* embyb = (u16*)alloc(32000L * 1024 * 2);
  if ((size_t)(p - (char*)d_ws) > ws_size) return;

  auto gemmF = [&](const u16* A, const u16* Bw, int M, int N, int K, int lda, int ldb,
                   const float* bias, const u16* residb, u16* C, int ldc) {
    dim3 g(N / 64, M / 64);
    gemm_k<64, 64, 0, 2, 128><<<g, 256, 0, stream>>>(A, nullptr, Bw, lda, ldb, K, bias,
                                                     residb, ldc, C, nullptr, nullptr,
                                                     nullptr, 0);
  };
  auto gemmRelu = [&](const u16* A, const u16* Bw, const float* bias, u16* C) {
    dim3 g(32, 16);
    gemm_k<128, 128, 1, 2, 64><<<g, 256, 0, stream>>>(A, nullptr, Bw, 1024, 1024, 1024, bias,
                                                      nullptr, 4096, C, nullptr, nullptr,
                                                      nullptr, 0);
  };
  auto gemmQKV = [&](const u16* A, const u16* Bw) {  // N=3072, single A
    dim3 g(24, 32);
    gemm_k<64, 128, 2, 3, 64><<<g, 256, 0, stream>>>(A, nullptr, Bw, 1024, 1024, 1024,
                                                     nullptr, nullptr, 0, nullptr, qb, kb,
                                                     vtb, 0);
  };
  auto gemmQKVx = [&](const u16* Aq, const u16* Akv, const u16* Bw) {  // cross, N=3072
    dim3 g(24, 32);
    gemm_k<64, 128, 3, 3, 64><<<g, 256, 0, stream>>>(Aq, Akv, Bw, 1024, 1024, 1024,
                                                     nullptr, nullptr, 0, nullptr, qb, kb,
                                                     vtb, 0);
  };
  auto attn = [&](const int* qids, const int* kids, int causal) {
    if (causal)
      fattn_k<1><<<dim3(4, 64), 512, 0, stream>>>(qb, kb, vtb, qids, kids, ctx);
    else
      fattn_k<0><<<dim3(4, 64), 512, 0, stream>>>(qb, kb, vtb, qids, kids, ctx);
  };
  auto lnorm = [&](const float* g, const float* b) {
    ln_k<<<2048, 256, 0, stream>>>(subb, g, b, ebf);
  };

  cvt_k<<<2048, 256, 0, stream>>>(emb_y, embyb, 32000 * 1024 / 4);

  // ---------------- encoder ----------------
  embed_k<<<2048, 256, 0, stream>>>(x_block, emb_x, ebf);
  for (int i = 0; i < 6; ++i) {
    cvt3_k<<<2048, 256, 0, stream>>>(enc_qkvo + (long)i * 4 * M1, (int)M1,
                                     enc_w1 + (long)i * 4 * M1, (int)M1,
                                     enc_w2 + (long)i * 4 * M1, (int)M1, wbuf);
    gemmQKV(ebf, wbuf);
    attn(x_block, x_block, 0);
    gemmF(ctx, wbuf + 3L * M1, 2048, 1024, 1024, 1024, 1024, nullptr, ebf, subb, 1024);
    lnorm(enc_ln_s + (i * 2 + 0) * 1024, enc_ln_b + (i * 2 + 0) * 1024);
    gemmRelu(ebf, wbuf + 4L * M1, enc_b1 + i * 4096, hbuf);
    gemmF(hbuf, wbuf + 8L * M1, 2048, 1024, 4096, 4096, 4096, enc_b2 + i * 1024, ebf,
          subb, 1024);
    lnorm(enc_ln_s + (i * 2 + 1) * 1024, enc_ln_b + (i * 2 + 1) * 1024);
  }
  hipMemcpyAsync(zbf, ebf, TOK * Dm * 2, hipMemcpyDeviceToDevice, stream);

  // ---------------- decoder ----------------
  embed_k<<<2048, 256, 0, stream>>>(y_block, emb_y, ebf);
  for (int i = 0; i < 6; ++i) {
    cvt3_k<<<2048, 256, 0, stream>>>(dec_qkvo + (long)i * 8 * M1, (int)(2 * M1),
                                     dec_w1 + (long)i * 4 * M1, (int)M1,
                                     dec_w2 + (long)i * 4 * M1, (int)M1, wbuf);
    // self-attention (causal)
    gemmQKV(ebf, wbuf);
    attn(y_block, y_block, 1);
    gemmF(ctx, wbuf + 3L * M1, 2048, 1024, 1024, 1024, 1024, nullptr, ebf, subb, 1024);
    lnorm(dec_ln_s + (i * 3 + 0) * 1024, dec_ln_b + (i * 3 + 0) * 1024);
    // cross-attention: Q from ebf, K/V from zbf, one merged dispatch
    gemmQKVx(ebf, zbf, wbuf + 4L * M1);
    attn(y_block, x_block, 0);
    gemmF(ctx, wbuf + 7L * M1, 2048, 1024, 1024, 1024, 1024, nullptr, ebf, subb, 1024);
    lnorm(dec_ln_s + (i * 3 + 1) * 1024, dec_ln_b + (i * 3 + 1) * 1024);
    // ffn
    gemmRelu(ebf, wbuf + 8L * M1, dec_b1 + i * 4096, hbuf);
    gemmF(hbuf, wbuf + 12L * M1, 2048, 1024, 4096, 4096, 4096, dec_b2 + i * 1024, ebf,
          subb, 1024);
    lnorm(dec_ln_s + (i * 3 + 2) * 1024, dec_ln_b + (i * 3 + 2) * 1024);
  }
  // final vocab projection -> d_out fp32 [B*SY, 32000] via 256^2 4-phase GEMM
  gemm256_k<<<dim3(125, 8), 512, 0, stream>>>(ebf, embyb, 1024, 1024, 1024,
                                              (float*)d_out, 32000);
}